// Round 4
// baseline (5314.849 us; speedup 1.0000x reference)
//
#include <hip/hip_runtime.h>
#include <hip/hip_cooperative_groups.h>

namespace cg = cooperative_groups;

// ---------------- problem constants (fixed by reference) ----------------
#define N_NODES 100000
#define N_EDGES 1600000
#define NG      512
#define NPART   8          // XCD partitions for scatter/count
#define NPP     12500      // nodes per partition (100000/8)
#define CHUNK_E 8192       // edges per block-chunk in partitioned kernels
#define MEGA_BLOCKS 1024
#define MEGA_NT (MEGA_BLOCKS * 256)

static __device__ __forceinline__ float lrelu(float v) {
    return v >= 0.0f ? v : 0.01f * v;
}

// ---------------- setup kernels ----------------
__global__ void k_zero_i32(int* __restrict__ p, int n) {
    int i = blockIdx.x * blockDim.x + threadIdx.x;
    if (i < n) p[i] = 0;
}

__global__ void k_copy_i32(const int* __restrict__ s, int* __restrict__ d, int n) {
    int i = blockIdx.x * blockDim.x + threadIdx.x;
    if (i < n) d[i] = s[i];
}

// partitioned degree count: block b -> partition b&7 (XCD-affine), chunk b>>3
// edge stream read non-temporally so it doesn't evict partition-local dirty lines
__global__ __launch_bounds__(256) void k_count_part(const int* __restrict__ edst,
                                                    int* __restrict__ counts) {
    int p = blockIdx.x & (NPART - 1);
    int chunk = blockIdx.x >> 3;
    int base = chunk * CHUNK_E;
    int plo = p * NPP, phi = plo + NPP;
    int end = base + CHUNK_E; if (end > N_EDGES) end = N_EDGES;
    for (int e = base + (int)threadIdx.x; e < end; e += 256) {
        int d = __builtin_nontemporal_load(&edst[e]);
        if (d >= plo && d < phi) atomicAdd(&counts[d], 1);
    }
}

// dinv = 1/sqrt(deg+1); dinv2 = 1/(deg+1); sdeg = sqrt(deg+1)
__global__ void k_dinv(const int* __restrict__ counts, float* __restrict__ dinv,
                       float* __restrict__ dinv2, float* __restrict__ sdeg) {
    int i = blockIdx.x * blockDim.x + threadIdx.x;
    if (i < N_NODES) {
        float deg = (float)(counts[i] + 1);
        float s = sqrtf(deg);
        sdeg[i] = s;
        dinv[i] = 1.0f / s;
        dinv2[i] = 1.0f / deg;
    }
}

// ---------------- exclusive scan (counts -> offsets) ----------------
__global__ void k_scan_block(const int* __restrict__ counts, int* __restrict__ offsets,
                             int* __restrict__ bsums, int n) {
    __shared__ int tmp[1024];
    int gid = blockIdx.x * 1024 + threadIdx.x;
    int v = (gid < n) ? counts[gid] : 0;
    tmp[threadIdx.x] = v;
    __syncthreads();
    for (int off = 1; off < 1024; off <<= 1) {
        int t = (threadIdx.x >= off) ? tmp[threadIdx.x - off] : 0;
        __syncthreads();
        tmp[threadIdx.x] += t;
        __syncthreads();
    }
    if (gid < n) offsets[gid + 1] = tmp[threadIdx.x];
    if (threadIdx.x == 1023) bsums[blockIdx.x] = tmp[1023];
}

__global__ void k_scan_bsums(int* __restrict__ bsums, int nb) {
    if (blockIdx.x == 0 && threadIdx.x == 0) {
        int acc = 0;
        for (int b = 0; b < nb; ++b) { int v = bsums[b]; bsums[b] = acc; acc += v; }
    }
}

__global__ void k_scan_add(int* __restrict__ offsets, const int* __restrict__ bsums, int n) {
    int gid = blockIdx.x * 1024 + threadIdx.x;
    if (gid < n) offsets[gid + 1] += bsums[blockIdx.x];
    if (gid == 0) offsets[0] = 0;
}

// partitioned CSR scatter with non-temporal edge-stream reads
__global__ __launch_bounds__(256) void k_scatter_part(
    const int* __restrict__ esrc, const int* __restrict__ edst,
    int* __restrict__ cursor, int* __restrict__ csr_src) {
    int p = blockIdx.x & (NPART - 1);
    int chunk = blockIdx.x >> 3;
    int base = chunk * CHUNK_E;
    int plo = p * NPP, phi = plo + NPP;
    int end = base + CHUNK_E; if (end > N_EDGES) end = N_EDGES;
    for (int e = base + (int)threadIdx.x; e < end; e += 256) {
        int d = __builtin_nontemporal_load(&edst[e]);
        if (d >= plo && d < phi) {
            int s = __builtin_nontemporal_load(&esrc[e]);
            int pos = atomicAdd(&cursor[d], 1);
            csr_src[pos] = s;
        }
    }
}

// ---------------- mega cooperative kernel: vinit + pass1 + s1 + pass2 + feats ----
struct MegaArgs {
    const float*  x;
    const float*  dinv;
    const float*  dinv2;
    const float*  sdeg;
    const int*    offs;
    const int*    csrc;
    float4*       v0;
    const float4* in1[16];    // pass-1 input per step
    float4*       out1[16];   // pass-1 output per step
    const float4* sv1[5];     // saved pass-1 levels 1,2,4,8,16
    float*        s1v;        // (N,12)
    const float4* in2[16];    // pass-2 input per step (3 float4 per node)
    float4*       out2[16];
    const float*  sv2[5];     // saved pass-2 levels (as float*)
    float*        feats;      // (N,33)
};

__global__ __launch_bounds__(256, 4) void k_mega(MegaArgs A) {
    cg::grid_group grid = cg::this_grid();
    const int tid = blockIdx.x * 256 + threadIdx.x;

    // phase 0: v = dinv .* x (float4-padded)
    for (int i = tid; i < N_NODES; i += MEGA_NT) {
        float di = A.dinv[i];
        A.v0[i] = make_float4(di * A.x[i * 3 + 0], di * A.x[i * 3 + 1],
                              di * A.x[i * 3 + 2], 0.0f);
    }
    grid.sync();

    // pass 1: 16 diffusion steps on (N,3), 4 edge-split lanes per node
    for (int t = 0; t < 16; ++t) {
        const float4* xin = A.in1[t];
        float4* xout = A.out1[t];
        for (int tt = tid; tt < N_NODES * 4; tt += MEGA_NT) {
            int h = tt & 3;
            int i = tt >> 2;
            int b = A.offs[i], e = A.offs[i + 1];
            float a0 = 0.0f, a1 = 0.0f, a2 = 0.0f;
            for (int p = b + h; p < e; p += 4) {
                int s = A.csrc[p];
                float4 xv = xin[s];
                a0 += xv.x; a1 += xv.y; a2 += xv.z;
            }
            a0 += __shfl_xor(a0, 1, 64); a1 += __shfl_xor(a1, 1, 64); a2 += __shfl_xor(a2, 1, 64);
            a0 += __shfl_xor(a0, 2, 64); a1 += __shfl_xor(a1, 2, 64); a2 += __shfl_xor(a2, 2, 64);
            if (h == 0) {
                float d2 = A.dinv2[i];
                float4 sv = xin[i];
                xout[i] = make_float4(0.5f * (sv.x + d2 * (a0 + sv.x)),
                                      0.5f * (sv.y + d2 * (a1 + sv.y)),
                                      0.5f * (sv.z + d2 * (a2 + sv.z)), 0.0f);
            }
        }
        grid.sync();
    }

    // s1 phase: s1v[i,c*4+f] = |L_f - L_{f+1}| (v-space; dinv factors cancel)
    for (int i = tid; i < N_NODES; i += MEGA_NT) {
        float4 v[5];
        v[0] = A.sv1[0][i]; v[1] = A.sv1[1][i]; v[2] = A.sv1[2][i];
        v[3] = A.sv1[3][i]; v[4] = A.sv1[4][i];
        float* out = A.s1v + (size_t)i * 12;
#pragma unroll
        for (int f = 0; f < 4; ++f) {
            out[0 * 4 + f] = fabsf(v[f].x - v[f + 1].x);
            out[1 * 4 + f] = fabsf(v[f].y - v[f + 1].y);
            out[2 * 4 + f] = fabsf(v[f].z - v[f + 1].z);
        }
    }
    grid.sync();

    // pass 2: 16 diffusion steps on (N,12)
    for (int t = 0; t < 16; ++t) {
        const float4* xin = A.in2[t];
        float4* xout = A.out2[t];
        for (int tt = tid; tt < N_NODES * 4; tt += MEGA_NT) {
            int h = tt & 3;
            int i = tt >> 2;
            int b = A.offs[i], e = A.offs[i + 1];
            float a[12];
#pragma unroll
            for (int c = 0; c < 12; ++c) a[c] = 0.0f;
            for (int p = b + h; p < e; p += 4) {
                int s = A.csrc[p];
                float4 b0 = xin[s * 3 + 0];
                float4 b1 = xin[s * 3 + 1];
                float4 b2 = xin[s * 3 + 2];
                a[0] += b0.x; a[1] += b0.y; a[2]  += b0.z; a[3]  += b0.w;
                a[4] += b1.x; a[5] += b1.y; a[6]  += b1.z; a[7]  += b1.w;
                a[8] += b2.x; a[9] += b2.y; a[10] += b2.z; a[11] += b2.w;
            }
#pragma unroll
            for (int c = 0; c < 12; ++c) {
                a[c] += __shfl_xor(a[c], 1, 64);
                a[c] += __shfl_xor(a[c], 2, 64);
            }
            if (h == 0) {
                float d2 = A.dinv2[i];
                float4 s0 = xin[i * 3 + 0], s1 = xin[i * 3 + 1], s2 = xin[i * 3 + 2];
                xout[i * 3 + 0] = make_float4(0.5f * (s0.x + d2 * (a[0] + s0.x)),
                                              0.5f * (s0.y + d2 * (a[1] + s0.y)),
                                              0.5f * (s0.z + d2 * (a[2] + s0.z)),
                                              0.5f * (s0.w + d2 * (a[3] + s0.w)));
                xout[i * 3 + 1] = make_float4(0.5f * (s1.x + d2 * (a[4] + s1.x)),
                                              0.5f * (s1.y + d2 * (a[5] + s1.y)),
                                              0.5f * (s1.z + d2 * (a[6] + s1.z)),
                                              0.5f * (s1.w + d2 * (a[7] + s1.w)));
                xout[i * 3 + 2] = make_float4(0.5f * (s2.x + d2 * (a[8] + s2.x)),
                                              0.5f * (s2.y + d2 * (a[9] + s2.y)),
                                              0.5f * (s2.z + d2 * (a[10] + s2.z)),
                                              0.5f * (s2.w + d2 * (a[11] + s2.w)));
            }
        }
        grid.sync();
    }

    // feats phase: (N,33) x-space features
    const int FENG[6] = {4, 8, 9, 12, 13, 14};
    for (int i = tid; i < N_NODES; i += MEGA_NT) {
        float sd = A.sdeg[i];
        float* out = A.feats + (size_t)i * 33;
        out[0] = A.x[i * 3 + 0];
        out[1] = A.x[i * 3 + 1];
        out[2] = A.x[i * 3 + 2];
        for (int r = 1; r <= 4; ++r)
            for (int c = 0; c < 3; ++c)
                out[r * 3 + c] = sd * A.s1v[(size_t)i * 12 + c * 4 + (r - 1)];
        for (int m = 0; m < 6; ++m) {
            for (int c2 = 0; c2 < 3; ++c2) {
                int idx = c2 * 16 + FENG[m];
                int w = idx / 12, rem = idx % 12, cc = rem / 4, f = rem % 4;
                float v = A.sv2[w][(size_t)i * 12 + cc * 4 + f] -
                          A.sv2[w + 1][(size_t)i * 12 + cc * 4 + f];
                out[(5 + m) * 3 + c2] = fabsf(sd * v);
            }
        }
    }
}

// ---------------- per-graph moments (batch sorted -> binary search range) --------
static __device__ __forceinline__ int lower_bound_i(const int* __restrict__ a, int n, int key) {
    int lo = 0, hi = n;
    while (lo < hi) { int mid = (lo + hi) >> 1; if (a[mid] < key) lo = mid + 1; else hi = mid; }
    return lo;
}

__global__ __launch_bounds__(256) void k_moments_mean(
    const float* __restrict__ feats, const int* __restrict__ batch,
    float* __restrict__ meanbuf) {
    __shared__ float part[4][33];
    int g = blockIdx.x;
    int lo = lower_bound_i(batch, N_NODES, g);
    int hi = lower_bound_i(batch, N_NODES, g + 1);
    float acc[33];
#pragma unroll
    for (int c = 0; c < 33; ++c) acc[c] = 0.0f;
    for (int i = lo + (int)threadIdx.x; i < hi; i += 256) {
        const float* f = feats + (size_t)i * 33;
#pragma unroll
        for (int c = 0; c < 33; ++c) acc[c] += f[c];
    }
#pragma unroll
    for (int c = 0; c < 33; ++c) {
        float v = acc[c];
        for (int o = 32; o >= 1; o >>= 1) v += __shfl_down(v, o, 64);
        acc[c] = v;
    }
    int wid = threadIdx.x >> 6, lane = threadIdx.x & 63;
    if (lane == 0)
        for (int c = 0; c < 33; ++c) part[wid][c] = acc[c];
    __syncthreads();
    if (threadIdx.x < 33) {
        float cnt = (float)((hi - lo) > 1 ? (hi - lo) : 1);
        float s = part[0][threadIdx.x] + part[1][threadIdx.x] +
                  part[2][threadIdx.x] + part[3][threadIdx.x];
        meanbuf[g * 33 + threadIdx.x] = s / cnt;
    }
}

__global__ __launch_bounds__(256) void k_moments_vs(
    const float* __restrict__ feats, const int* __restrict__ batch,
    const float* __restrict__ meanbuf, float* __restrict__ h0) {
    __shared__ float part2[4][33];
    __shared__ float part3[4][33];
    int g = blockIdx.x;
    int lo = lower_bound_i(batch, N_NODES, g);
    int hi = lower_bound_i(batch, N_NODES, g + 1);
    float mu[33], a2[33], a3[33];
#pragma unroll
    for (int c = 0; c < 33; ++c) { mu[c] = meanbuf[g * 33 + c]; a2[c] = 0.0f; a3[c] = 0.0f; }
    for (int i = lo + (int)threadIdx.x; i < hi; i += 256) {
        const float* f = feats + (size_t)i * 33;
#pragma unroll
        for (int c = 0; c < 33; ++c) {
            float d = f[c] - mu[c];
            float d2 = d * d;
            a2[c] += d2;
            a3[c] += d2 * d;
        }
    }
#pragma unroll
    for (int c = 0; c < 33; ++c) {
        float v2 = a2[c], v3 = a3[c];
        for (int o = 32; o >= 1; o >>= 1) {
            v2 += __shfl_down(v2, o, 64);
            v3 += __shfl_down(v3, o, 64);
        }
        a2[c] = v2; a3[c] = v3;
    }
    int wid = threadIdx.x >> 6, lane = threadIdx.x & 63;
    if (lane == 0)
        for (int c = 0; c < 33; ++c) { part2[wid][c] = a2[c]; part3[wid][c] = a3[c]; }
    __syncthreads();
    if (threadIdx.x < 33) {
        int c = threadIdx.x;
        float cnt = (float)((hi - lo) > 1 ? (hi - lo) : 1);
        float v2 = part2[0][c] + part2[1][c] + part2[2][c] + part2[3][c];
        float v3 = part3[0][c] + part3[1][c] + part3[2][c] + part3[3][c];
        h0[g * 99 + c]      = lrelu(mu[c]);
        h0[g * 99 + 33 + c] = lrelu(v2 / cnt);
        h0[g * 99 + 66 + c] = lrelu(v3 / cnt);
    }
}

// ---------------- fused per-graph MLP: h0(99)->128->64->64->emb(32)->out(1) ------
__global__ __launch_bounds__(128) void k_mlp(
    const float* __restrict__ h0,
    const float* __restrict__ W1, const float* __restrict__ b1,
    const float* __restrict__ W2, const float* __restrict__ b2,
    const float* __restrict__ W3, const float* __restrict__ b3,
    const float* __restrict__ We, const float* __restrict__ be,
    const float* __restrict__ Wc, const float* __restrict__ bc,
    float* __restrict__ emb, float* __restrict__ outp) {
    __shared__ float s0[99], s1[128], s2[64], s3[64], s4[32];
    int g = blockIdx.x;
    int t = threadIdx.x;
    if (t < 99) s0[t] = h0[g * 99 + t];
    __syncthreads();
    {
        float a = b1[t];
        for (int k = 0; k < 99; ++k) a += s0[k] * W1[k * 128 + t];
        s1[t] = lrelu(a);
    }
    __syncthreads();
    if (t < 64) {
        float a = b2[t];
        for (int k = 0; k < 128; ++k) a += s1[k] * W2[k * 64 + t];
        s2[t] = lrelu(a);
    }
    __syncthreads();
    if (t < 64) {
        float a = b3[t];
        for (int k = 0; k < 64; ++k) a += s2[k] * W3[k * 64 + t];
        s3[t] = a;
    }
    __syncthreads();
    if (t < 32) {
        float a = be[t];
        for (int k = 0; k < 64; ++k) a += s3[k] * We[k * 32 + t];
        s4[t] = a;
        emb[g * 32 + t] = a;
    }
    __syncthreads();
    if (t == 0) {
        float a = bc[0];
        for (int k = 0; k < 32; ++k) a += s4[k] * Wc[k];
        outp[g] = a;
    }
}

// ---------------- host ----------------
extern "C" void kernel_launch(void* const* d_in, const int* in_sizes, int n_in,
                              void* d_out, int out_size, void* d_ws, size_t ws_size,
                              hipStream_t stream) {
    const float* x   = (const float*)d_in[0];
    const float* W1  = (const float*)d_in[1];
    const float* b1  = (const float*)d_in[2];
    const float* W2  = (const float*)d_in[3];
    const float* b2  = (const float*)d_in[4];
    const float* W3  = (const float*)d_in[5];
    const float* b3  = (const float*)d_in[6];
    const float* We  = (const float*)d_in[7];
    const float* be  = (const float*)d_in[8];
    const float* Wc  = (const float*)d_in[9];
    const float* bc  = (const float*)d_in[10];
    const int*   eix = (const int*)d_in[11];
    const int*   batch = (const int*)d_in[12];
    const int* esrc = eix;
    const int* edst = eix + N_EDGES;

    char* ws = (char*)d_ws;
    size_t off = 0;
    auto alloc = [&](size_t bytes) -> void* {
        void* p = ws + off;
        off = (off + bytes + 255) & ~(size_t)255;
        return p;
    };
    int*   counts  = (int*)alloc((size_t)N_NODES * 4);
    int*   offsets = (int*)alloc((size_t)(N_NODES + 1) * 4);
    int*   cursor  = (int*)alloc((size_t)N_NODES * 4);
    float* dinv    = (float*)alloc((size_t)N_NODES * 4);
    float* dinv2   = (float*)alloc((size_t)N_NODES * 4);
    float* sdeg    = (float*)alloc((size_t)N_NODES * 4);
    int*   bsums   = (int*)alloc(1024 * 4);
    int*   csr_src = (int*)alloc((size_t)N_EDGES * 4);
    float4* v0     = (float4*)alloc((size_t)N_NODES * 16);
    float4* p1[7];
    for (int i = 0; i < 7; ++i) p1[i] = (float4*)alloc((size_t)N_NODES * 16);
    float* s1v = (float*)alloc((size_t)N_NODES * 12 * 4);
    float* p2[7];
    for (int i = 0; i < 7; ++i) p2[i] = (float*)alloc((size_t)N_NODES * 12 * 4);
    float* feats = (float*)alloc((size_t)N_NODES * 33 * 4);
    float* meanb = (float*)alloc((size_t)NG * 33 * 4);
    float* h0 = (float*)alloc((size_t)NG * 99 * 4);
    (void)ws_size; (void)in_sizes; (void)n_in; (void)out_size;

    const int TB = 256;
    const int gbN = (N_NODES + TB - 1) / TB;
    const int nbScan = (N_NODES + 1023) / 1024;
    const int nChunks = (N_EDGES + CHUNK_E - 1) / CHUNK_E;
    const int gbPart = nChunks * NPART;

    // --- GCN normalization + CSR build (XCD-partitioned, nt edge streams) ---
    hipLaunchKernelGGL(k_zero_i32, dim3(gbN), dim3(TB), 0, stream, counts, N_NODES);
    hipLaunchKernelGGL(k_count_part, dim3(gbPart), dim3(TB), 0, stream, edst, counts);
    hipLaunchKernelGGL(k_dinv, dim3(gbN), dim3(TB), 0, stream, counts, dinv, dinv2, sdeg);
    hipLaunchKernelGGL(k_scan_block, dim3(nbScan), dim3(1024), 0, stream, counts, offsets, bsums, N_NODES);
    hipLaunchKernelGGL(k_scan_bsums, dim3(1), dim3(1), 0, stream, bsums, nbScan);
    hipLaunchKernelGGL(k_scan_add, dim3(nbScan), dim3(1024), 0, stream, offsets, bsums, N_NODES);
    hipLaunchKernelGGL(k_copy_i32, dim3(gbN), dim3(TB), 0, stream, offsets, cursor, N_NODES);
    hipLaunchKernelGGL(k_scatter_part, dim3(gbPart), dim3(TB), 0, stream, esrc, edst, cursor, csr_src);

    // --- build mega-kernel buffer schedule (same ping-pong as before) ---
    MegaArgs A;
    A.x = x; A.dinv = dinv; A.dinv2 = dinv2; A.sdeg = sdeg;
    A.offs = offsets; A.csrc = csr_src;
    A.v0 = v0; A.s1v = s1v; A.feats = feats;
    const int saveT[5] = {1, 2, 4, 8, 16};
    {
        const float4* prev = v0;
        int si = 0, sc = 0;
        for (int t = 1; t <= 16; ++t) {
            float4* outb;
            if (si < 5 && t == saveT[si]) { outb = p1[si]; A.sv1[si] = outb; ++si; }
            else { outb = p1[5 + sc]; sc ^= 1; }
            A.in1[t - 1] = prev;
            A.out1[t - 1] = outb;
            prev = outb;
        }
    }
    {
        const float* prev2 = s1v;
        int si = 0, sc = 0;
        for (int t = 1; t <= 16; ++t) {
            float* outb;
            if (si < 5 && t == saveT[si]) { outb = p2[si]; A.sv2[si] = outb; ++si; }
            else { outb = p2[5 + sc]; sc ^= 1; }
            A.in2[t - 1] = (const float4*)prev2;
            A.out2[t - 1] = (float4*)outb;
            prev2 = outb;
        }
    }

    void* kargs[] = { (void*)&A };
    hipLaunchCooperativeKernel((const void*)k_mega, dim3(MEGA_BLOCKS), dim3(256),
                               kargs, 0, stream);

    // --- moments + fused MLP ---
    float* emb  = (float*)d_out;            // (512,32)
    float* outp = (float*)d_out + NG * 32;  // (512,1)
    hipLaunchKernelGGL(k_moments_mean, dim3(NG), dim3(256), 0, stream, feats, batch, meanb);
    hipLaunchKernelGGL(k_moments_vs, dim3(NG), dim3(256), 0, stream, feats, batch, meanb, h0);
    hipLaunchKernelGGL(k_mlp, dim3(NG), dim3(128), 0, stream,
                       h0, W1, b1, W2, b2, W3, b3, We, be, Wc, bc, emb, outp);
}

// Round 5
// 832.493 us; speedup vs baseline: 6.3843x; 6.3843x over previous
//
#include <hip/hip_runtime.h>

// ---------------- problem constants (fixed by reference) ----------------
#define N_NODES 100000
#define N_EDGES 1600000
#define NG      512
#define NPART   8          // XCD partitions for scatter/count
#define NPP     12500      // nodes per partition (100000/8)
#define CHUNK_E 8192       // edges per block-chunk in partitioned kernels

static __device__ __forceinline__ float lrelu(float v) {
    return v >= 0.0f ? v : 0.01f * v;
}

// ---------------- setup kernels ----------------
__global__ void k_zero_i32(int* __restrict__ p, int n) {
    int i = blockIdx.x * blockDim.x + threadIdx.x;
    if (i < n) p[i] = 0;
}

__global__ void k_copy_i32(const int* __restrict__ s, int* __restrict__ d, int n) {
    int i = blockIdx.x * blockDim.x + threadIdx.x;
    if (i < n) d[i] = s[i];
}

// partitioned degree count: block b -> partition b&7 (XCD-affine), chunk b>>3
// edge stream read non-temporally so it doesn't evict partition-local dirty lines
__global__ __launch_bounds__(256) void k_count_part(const int* __restrict__ edst,
                                                    int* __restrict__ counts) {
    int p = blockIdx.x & (NPART - 1);
    int chunk = blockIdx.x >> 3;
    int base = chunk * CHUNK_E;
    int plo = p * NPP, phi = plo + NPP;
    int end = base + CHUNK_E; if (end > N_EDGES) end = N_EDGES;
    for (int e = base + (int)threadIdx.x; e < end; e += 256) {
        int d = __builtin_nontemporal_load(&edst[e]);
        if (d >= plo && d < phi) atomicAdd(&counts[d], 1);
    }
}

// dinv = 1/sqrt(deg+1); dinv2 = 1/(deg+1); sdeg = sqrt(deg+1)
__global__ void k_dinv(const int* __restrict__ counts, float* __restrict__ dinv,
                       float* __restrict__ dinv2, float* __restrict__ sdeg) {
    int i = blockIdx.x * blockDim.x + threadIdx.x;
    if (i < N_NODES) {
        float deg = (float)(counts[i] + 1);
        float s = sqrtf(deg);
        sdeg[i] = s;
        dinv[i] = 1.0f / s;
        dinv2[i] = 1.0f / deg;
    }
}

// ---------------- exclusive scan (counts -> offsets) ----------------
__global__ void k_scan_block(const int* __restrict__ counts, int* __restrict__ offsets,
                             int* __restrict__ bsums, int n) {
    __shared__ int tmp[1024];
    int gid = blockIdx.x * 1024 + threadIdx.x;
    int v = (gid < n) ? counts[gid] : 0;
    tmp[threadIdx.x] = v;
    __syncthreads();
    for (int off = 1; off < 1024; off <<= 1) {
        int t = (threadIdx.x >= off) ? tmp[threadIdx.x - off] : 0;
        __syncthreads();
        tmp[threadIdx.x] += t;
        __syncthreads();
    }
    if (gid < n) offsets[gid + 1] = tmp[threadIdx.x];
    if (threadIdx.x == 1023) bsums[blockIdx.x] = tmp[1023];
}

__global__ void k_scan_bsums(int* __restrict__ bsums, int nb) {
    if (blockIdx.x == 0 && threadIdx.x == 0) {
        int acc = 0;
        for (int b = 0; b < nb; ++b) { int v = bsums[b]; bsums[b] = acc; acc += v; }
    }
}

__global__ void k_scan_add(int* __restrict__ offsets, const int* __restrict__ bsums, int n) {
    int gid = blockIdx.x * 1024 + threadIdx.x;
    if (gid < n) offsets[gid + 1] += bsums[blockIdx.x];
    if (gid == 0) offsets[0] = 0;
}

// partitioned CSR scatter with non-temporal edge-stream reads
__global__ __launch_bounds__(256) void k_scatter_part(
    const int* __restrict__ esrc, const int* __restrict__ edst,
    int* __restrict__ cursor, int* __restrict__ csr_src) {
    int p = blockIdx.x & (NPART - 1);
    int chunk = blockIdx.x >> 3;
    int base = chunk * CHUNK_E;
    int plo = p * NPP, phi = plo + NPP;
    int end = base + CHUNK_E; if (end > N_EDGES) end = N_EDGES;
    for (int e = base + (int)threadIdx.x; e < end; e += 256) {
        int d = __builtin_nontemporal_load(&edst[e]);
        if (d >= plo && d < phi) {
            int s = __builtin_nontemporal_load(&esrc[e]);
            int pos = atomicAdd(&cursor[d], 1);
            csr_src[pos] = s;
        }
    }
}

// ---------------- v-space init: v = dinv .* x, padded to float4 ----------------
__global__ void k_vinit(const float* __restrict__ x, const float* __restrict__ dinv,
                        float4* __restrict__ v) {
    int i = blockIdx.x * blockDim.x + threadIdx.x;
    if (i >= N_NODES) return;
    float di = dinv[i];
    v[i] = make_float4(di * x[i * 3 + 0], di * x[i * 3 + 1], di * x[i * 3 + 2], 0.0f);
}

// ---------------- diffusion (v-space): v' = 0.5*(v + dinv2*(sum_nbr + v)) --------
// pass 1: float4 node state, 8 edge-split lanes per node -> 800K threads
__global__ __launch_bounds__(256) void k_vdiff3(
    const float4* __restrict__ xin, float4* __restrict__ xout,
    const int* __restrict__ offs, const int* __restrict__ csrc,
    const float* __restrict__ dinv2) {
    int t = blockIdx.x * 256 + threadIdx.x;
    if (t >= N_NODES * 8) return;
    int h = t & 7;
    int i = t >> 3;
    int b = offs[i], e = offs[i + 1];
    float a0 = 0.0f, a1 = 0.0f, a2 = 0.0f;
    for (int p = b + h; p < e; p += 8) {
        int s = csrc[p];
        float4 xv = xin[s];
        a0 += xv.x; a1 += xv.y; a2 += xv.z;
    }
    a0 += __shfl_xor(a0, 1, 64); a1 += __shfl_xor(a1, 1, 64); a2 += __shfl_xor(a2, 1, 64);
    a0 += __shfl_xor(a0, 2, 64); a1 += __shfl_xor(a1, 2, 64); a2 += __shfl_xor(a2, 2, 64);
    a0 += __shfl_xor(a0, 4, 64); a1 += __shfl_xor(a1, 4, 64); a2 += __shfl_xor(a2, 4, 64);
    if (h == 0) {
        float d2 = dinv2[i];
        float4 sv = xin[i];
        xout[i] = make_float4(0.5f * (sv.x + d2 * (a0 + sv.x)),
                              0.5f * (sv.y + d2 * (a1 + sv.y)),
                              0.5f * (sv.z + d2 * (a2 + sv.z)), 0.0f);
    }
}

// pass 2: 12 channels per thread, 8 edge-split lanes per node -> 800K threads
__global__ __launch_bounds__(256) void k_vdiff12(
    const float4* __restrict__ xin, float4* __restrict__ xout,
    const int* __restrict__ offs, const int* __restrict__ csrc,
    const float* __restrict__ dinv2) {
    int t = blockIdx.x * 256 + threadIdx.x;
    if (t >= N_NODES * 8) return;
    int h = t & 7;
    int i = t >> 3;
    int b = offs[i], e = offs[i + 1];
    float a[12];
#pragma unroll
    for (int c = 0; c < 12; ++c) a[c] = 0.0f;
    for (int p = b + h; p < e; p += 8) {
        int s = csrc[p];
        float4 b0 = xin[s * 3 + 0];
        float4 b1 = xin[s * 3 + 1];
        float4 b2 = xin[s * 3 + 2];
        a[0] += b0.x; a[1] += b0.y; a[2]  += b0.z; a[3]  += b0.w;
        a[4] += b1.x; a[5] += b1.y; a[6]  += b1.z; a[7]  += b1.w;
        a[8] += b2.x; a[9] += b2.y; a[10] += b2.z; a[11] += b2.w;
    }
#pragma unroll
    for (int c = 0; c < 12; ++c) {
        a[c] += __shfl_xor(a[c], 1, 64);
        a[c] += __shfl_xor(a[c], 2, 64);
        a[c] += __shfl_xor(a[c], 4, 64);
    }
    if (h == 0) {
        float d2 = dinv2[i];
        float4 s0 = xin[i * 3 + 0], s1 = xin[i * 3 + 1], s2 = xin[i * 3 + 2];
        xout[i * 3 + 0] = make_float4(0.5f * (s0.x + d2 * (a[0] + s0.x)),
                                      0.5f * (s0.y + d2 * (a[1] + s0.y)),
                                      0.5f * (s0.z + d2 * (a[2] + s0.z)),
                                      0.5f * (s0.w + d2 * (a[3] + s0.w)));
        xout[i * 3 + 1] = make_float4(0.5f * (s1.x + d2 * (a[4] + s1.x)),
                                      0.5f * (s1.y + d2 * (a[5] + s1.y)),
                                      0.5f * (s1.z + d2 * (a[6] + s1.z)),
                                      0.5f * (s1.w + d2 * (a[7] + s1.w)));
        xout[i * 3 + 2] = make_float4(0.5f * (s2.x + d2 * (a[8] + s2.x)),
                                      0.5f * (s2.y + d2 * (a[9] + s2.y)),
                                      0.5f * (s2.z + d2 * (a[10] + s2.z)),
                                      0.5f * (s2.w + d2 * (a[11] + s2.w)));
    }
}

// ---------------- s1 in v-space: |vL[f]-vL[f+1]| (float4-padded levels in) -------
__global__ void k_s1v(const float4* __restrict__ L1, const float4* __restrict__ L2,
                      const float4* __restrict__ L4, const float4* __restrict__ L8,
                      const float4* __restrict__ L16, float* __restrict__ s1v) {
    int i = blockIdx.x * blockDim.x + threadIdx.x;
    if (i >= N_NODES) return;
    float4 v[5];
    v[0] = L1[i]; v[1] = L2[i]; v[2] = L4[i]; v[3] = L8[i]; v[4] = L16[i];
    float* out = s1v + (size_t)i * 12;
#pragma unroll
    for (int f = 0; f < 4; ++f) {
        out[0 * 4 + f] = fabsf(v[f].x - v[f + 1].x);
        out[1 * 4 + f] = fabsf(v[f].y - v[f + 1].y);
        out[2 * 4 + f] = fabsf(v[f].z - v[f + 1].z);
    }
}

// ---------------- feats (N,33), converting v-space -> x-space via sdeg -----------
__global__ void k_feats(const float* __restrict__ x, const float* __restrict__ s1v,
                        const float* __restrict__ M1, const float* __restrict__ M2,
                        const float* __restrict__ M4, const float* __restrict__ M8,
                        const float* __restrict__ M16, const float* __restrict__ sdeg,
                        float* __restrict__ feats) {
    int i = blockIdx.x * blockDim.x + threadIdx.x;
    if (i >= N_NODES) return;
    float sd = sdeg[i];
    float* out = feats + (size_t)i * 33;
    out[0] = x[i * 3 + 0];
    out[1] = x[i * 3 + 1];
    out[2] = x[i * 3 + 2];
    // r=1..4 : s1_x[n, c, r-1] = sdeg * s1v[n, c*4 + (r-1)]
    for (int r = 1; r <= 4; ++r)
        for (int c = 0; c < 3; ++c)
            out[r * 3 + c] = sd * s1v[(size_t)i * 12 + c * 4 + (r - 1)];
    // r=5..10 : s2[n, m, c2]; flat idx = c2*16 + FENG[m]; flat = w*12 + cc*4 + f
    const float* Ms[5] = {M1, M2, M4, M8, M16};
    const int FENG[6] = {4, 8, 9, 12, 13, 14};
    for (int m = 0; m < 6; ++m) {
        for (int c2 = 0; c2 < 3; ++c2) {
            int idx = c2 * 16 + FENG[m];
            int w = idx / 12, rem = idx % 12, cc = rem / 4, f = rem % 4;
            float v = Ms[w][(size_t)i * 12 + cc * 4 + f] - Ms[w + 1][(size_t)i * 12 + cc * 4 + f];
            out[(5 + m) * 3 + c2] = fabsf(sd * v);
        }
    }
}

// ---------------- per-graph moments (batch sorted -> binary search range) --------
static __device__ __forceinline__ int lower_bound_i(const int* __restrict__ a, int n, int key) {
    int lo = 0, hi = n;
    while (lo < hi) { int mid = (lo + hi) >> 1; if (a[mid] < key) lo = mid + 1; else hi = mid; }
    return lo;
}

__global__ __launch_bounds__(256) void k_moments_mean(
    const float* __restrict__ feats, const int* __restrict__ batch,
    float* __restrict__ meanbuf) {
    __shared__ float part[4][33];
    int g = blockIdx.x;
    int lo = lower_bound_i(batch, N_NODES, g);
    int hi = lower_bound_i(batch, N_NODES, g + 1);
    float acc[33];
#pragma unroll
    for (int c = 0; c < 33; ++c) acc[c] = 0.0f;
    for (int i = lo + (int)threadIdx.x; i < hi; i += 256) {
        const float* f = feats + (size_t)i * 33;
#pragma unroll
        for (int c = 0; c < 33; ++c) acc[c] += f[c];
    }
#pragma unroll
    for (int c = 0; c < 33; ++c) {
        float v = acc[c];
        for (int o = 32; o >= 1; o >>= 1) v += __shfl_down(v, o, 64);
        acc[c] = v;
    }
    int wid = threadIdx.x >> 6, lane = threadIdx.x & 63;
    if (lane == 0)
        for (int c = 0; c < 33; ++c) part[wid][c] = acc[c];
    __syncthreads();
    if (threadIdx.x < 33) {
        float cnt = (float)((hi - lo) > 1 ? (hi - lo) : 1);
        float s = part[0][threadIdx.x] + part[1][threadIdx.x] +
                  part[2][threadIdx.x] + part[3][threadIdx.x];
        meanbuf[g * 33 + threadIdx.x] = s / cnt;
    }
}

__global__ __launch_bounds__(256) void k_moments_vs(
    const float* __restrict__ feats, const int* __restrict__ batch,
    const float* __restrict__ meanbuf, float* __restrict__ h0) {
    __shared__ float part2[4][33];
    __shared__ float part3[4][33];
    int g = blockIdx.x;
    int lo = lower_bound_i(batch, N_NODES, g);
    int hi = lower_bound_i(batch, N_NODES, g + 1);
    float mu[33], a2[33], a3[33];
#pragma unroll
    for (int c = 0; c < 33; ++c) { mu[c] = meanbuf[g * 33 + c]; a2[c] = 0.0f; a3[c] = 0.0f; }
    for (int i = lo + (int)threadIdx.x; i < hi; i += 256) {
        const float* f = feats + (size_t)i * 33;
#pragma unroll
        for (int c = 0; c < 33; ++c) {
            float d = f[c] - mu[c];
            float d2 = d * d;
            a2[c] += d2;
            a3[c] += d2 * d;
        }
    }
#pragma unroll
    for (int c = 0; c < 33; ++c) {
        float v2 = a2[c], v3 = a3[c];
        for (int o = 32; o >= 1; o >>= 1) {
            v2 += __shfl_down(v2, o, 64);
            v3 += __shfl_down(v3, o, 64);
        }
        a2[c] = v2; a3[c] = v3;
    }
    int wid = threadIdx.x >> 6, lane = threadIdx.x & 63;
    if (lane == 0)
        for (int c = 0; c < 33; ++c) { part2[wid][c] = a2[c]; part3[wid][c] = a3[c]; }
    __syncthreads();
    if (threadIdx.x < 33) {
        int c = threadIdx.x;
        float cnt = (float)((hi - lo) > 1 ? (hi - lo) : 1);
        float v2 = part2[0][c] + part2[1][c] + part2[2][c] + part2[3][c];
        float v3 = part3[0][c] + part3[1][c] + part3[2][c] + part3[3][c];
        h0[g * 99 + c]      = lrelu(mu[c]);
        h0[g * 99 + 33 + c] = lrelu(v2 / cnt);
        h0[g * 99 + 66 + c] = lrelu(v3 / cnt);
    }
}

// ---------------- fused per-graph MLP: h0(99)->128->64->64->emb(32)->out(1) ------
__global__ __launch_bounds__(128) void k_mlp(
    const float* __restrict__ h0,
    const float* __restrict__ W1, const float* __restrict__ b1,
    const float* __restrict__ W2, const float* __restrict__ b2,
    const float* __restrict__ W3, const float* __restrict__ b3,
    const float* __restrict__ We, const float* __restrict__ be,
    const float* __restrict__ Wc, const float* __restrict__ bc,
    float* __restrict__ emb, float* __restrict__ outp) {
    __shared__ float s0[99], s1[128], s2[64], s3[64], s4[32];
    int g = blockIdx.x;
    int t = threadIdx.x;
    if (t < 99) s0[t] = h0[g * 99 + t];
    __syncthreads();
    {
        float a = b1[t];
        for (int k = 0; k < 99; ++k) a += s0[k] * W1[k * 128 + t];
        s1[t] = lrelu(a);
    }
    __syncthreads();
    if (t < 64) {
        float a = b2[t];
        for (int k = 0; k < 128; ++k) a += s1[k] * W2[k * 64 + t];
        s2[t] = lrelu(a);
    }
    __syncthreads();
    if (t < 64) {
        float a = b3[t];
        for (int k = 0; k < 64; ++k) a += s2[k] * W3[k * 64 + t];
        s3[t] = a;
    }
    __syncthreads();
    if (t < 32) {
        float a = be[t];
        for (int k = 0; k < 64; ++k) a += s3[k] * We[k * 32 + t];
        s4[t] = a;
        emb[g * 32 + t] = a;
    }
    __syncthreads();
    if (t == 0) {
        float a = bc[0];
        for (int k = 0; k < 32; ++k) a += s4[k] * Wc[k];
        outp[g] = a;
    }
}

// ---------------- host ----------------
extern "C" void kernel_launch(void* const* d_in, const int* in_sizes, int n_in,
                              void* d_out, int out_size, void* d_ws, size_t ws_size,
                              hipStream_t stream) {
    const float* x   = (const float*)d_in[0];
    const float* W1  = (const float*)d_in[1];
    const float* b1  = (const float*)d_in[2];
    const float* W2  = (const float*)d_in[3];
    const float* b2  = (const float*)d_in[4];
    const float* W3  = (const float*)d_in[5];
    const float* b3  = (const float*)d_in[6];
    const float* We  = (const float*)d_in[7];
    const float* be  = (const float*)d_in[8];
    const float* Wc  = (const float*)d_in[9];
    const float* bc  = (const float*)d_in[10];
    const int*   eix = (const int*)d_in[11];
    const int*   batch = (const int*)d_in[12];
    const int* esrc = eix;
    const int* edst = eix + N_EDGES;

    char* ws = (char*)d_ws;
    size_t off = 0;
    auto alloc = [&](size_t bytes) -> void* {
        void* p = ws + off;
        off = (off + bytes + 255) & ~(size_t)255;
        return p;
    };
    int*   counts  = (int*)alloc((size_t)N_NODES * 4);
    int*   offsets = (int*)alloc((size_t)(N_NODES + 1) * 4);
    int*   cursor  = (int*)alloc((size_t)N_NODES * 4);
    float* dinv    = (float*)alloc((size_t)N_NODES * 4);
    float* dinv2   = (float*)alloc((size_t)N_NODES * 4);
    float* sdeg    = (float*)alloc((size_t)N_NODES * 4);
    int*   bsums   = (int*)alloc(1024 * 4);
    int*   csr_src = (int*)alloc((size_t)N_EDGES * 4);
    float4* v0     = (float4*)alloc((size_t)N_NODES * 16);
    float4* p1[7];
    for (int i = 0; i < 7; ++i) p1[i] = (float4*)alloc((size_t)N_NODES * 16);
    float* s1v = (float*)alloc((size_t)N_NODES * 12 * 4);
    float* p2[7];
    for (int i = 0; i < 7; ++i) p2[i] = (float*)alloc((size_t)N_NODES * 12 * 4);
    float* feats = (float*)alloc((size_t)N_NODES * 33 * 4);
    float* meanb = (float*)alloc((size_t)NG * 33 * 4);
    float* h0 = (float*)alloc((size_t)NG * 99 * 4);
    (void)ws_size; (void)in_sizes; (void)n_in; (void)out_size;

    const int TB = 256;
    const int gbN = (N_NODES + TB - 1) / TB;
    const int nbScan = (N_NODES + 1023) / 1024;
    const int nChunks = (N_EDGES + CHUNK_E - 1) / CHUNK_E;
    const int gbPart = nChunks * NPART;

    // --- GCN normalization + CSR build (XCD-partitioned, nt edge streams) ---
    hipLaunchKernelGGL(k_zero_i32, dim3(gbN), dim3(TB), 0, stream, counts, N_NODES);
    hipLaunchKernelGGL(k_count_part, dim3(gbPart), dim3(TB), 0, stream, edst, counts);
    hipLaunchKernelGGL(k_dinv, dim3(gbN), dim3(TB), 0, stream, counts, dinv, dinv2, sdeg);
    hipLaunchKernelGGL(k_scan_block, dim3(nbScan), dim3(1024), 0, stream, counts, offsets, bsums, N_NODES);
    hipLaunchKernelGGL(k_scan_bsums, dim3(1), dim3(1), 0, stream, bsums, nbScan);
    hipLaunchKernelGGL(k_scan_add, dim3(nbScan), dim3(1024), 0, stream, offsets, bsums, N_NODES);
    hipLaunchKernelGGL(k_copy_i32, dim3(gbN), dim3(TB), 0, stream, offsets, cursor, N_NODES);
    hipLaunchKernelGGL(k_scatter_part, dim3(gbPart), dim3(TB), 0, stream, esrc, edst, cursor, csr_src);

    // --- v-space init (float4-padded) ---
    hipLaunchKernelGGL(k_vinit, dim3(gbN), dim3(TB), 0, stream, x, dinv, v0);

    const int saveT[5] = {1, 2, 4, 8, 16};

    // --- pass 1: diffuse (N,3) in v-space, save levels 1,2,4,8,16 ---
    const float4* prev = v0;
    float4* saves1[5];
    {
        int si = 0, sc = 0;
        const int gb = (N_NODES * 8 + TB - 1) / TB;
        for (int t = 1; t <= 16; ++t) {
            float4* outb;
            if (si < 5 && t == saveT[si]) { outb = p1[si]; saves1[si] = outb; ++si; }
            else { outb = p1[5 + sc]; sc ^= 1; }
            hipLaunchKernelGGL(k_vdiff3, dim3(gb), dim3(TB), 0, stream,
                               prev, outb, offsets, csr_src, dinv2);
            prev = outb;
        }
    }
    hipLaunchKernelGGL(k_s1v, dim3(gbN), dim3(TB), 0, stream,
                       saves1[0], saves1[1], saves1[2], saves1[3], saves1[4], s1v);

    // --- pass 2: diffuse (N,12) in v-space, save levels 1,2,4,8,16 ---
    float* saves2[5];
    {
        const float* prev2 = s1v;  // v2_0 = |v-differences| = s1v (dinv factors cancel)
        int si = 0, sc = 0;
        const int gb = (N_NODES * 8 + TB - 1) / TB;
        for (int t = 1; t <= 16; ++t) {
            float* outb;
            if (si < 5 && t == saveT[si]) { outb = p2[si]; saves2[si] = outb; ++si; }
            else { outb = p2[5 + sc]; sc ^= 1; }
            hipLaunchKernelGGL(k_vdiff12, dim3(gb), dim3(TB), 0, stream,
                               (const float4*)prev2, (float4*)outb, offsets, csr_src, dinv2);
            prev2 = outb;
        }
    }

    // --- features + moments ---
    hipLaunchKernelGGL(k_feats, dim3(gbN), dim3(TB), 0, stream,
                       x, s1v, saves2[0], saves2[1], saves2[2], saves2[3], saves2[4], sdeg, feats);
    hipLaunchKernelGGL(k_moments_mean, dim3(NG), dim3(256), 0, stream, feats, batch, meanb);
    hipLaunchKernelGGL(k_moments_vs, dim3(NG), dim3(256), 0, stream, feats, batch, meanb, h0);

    // --- fused MLP head ---
    float* emb  = (float*)d_out;            // (512,32)
    float* outp = (float*)d_out + NG * 32;  // (512,1)
    hipLaunchKernelGGL(k_mlp, dim3(NG), dim3(128), 0, stream,
                       h0, W1, b1, W2, b2, W3, b3, We, be, Wc, bc, emb, outp);
}